// Round 15
// baseline (647.039 us; speedup 1.0000x reference)
//
#include <hip/hip_runtime.h>
#include <hip/hip_cooperative_groups.h>

namespace cg = cooperative_groups;

#define BS        64
#define W_TOTAL_C 2234368
#define B_TOTAL_C 3526

__device__ __forceinline__ float silu_f(float v) {
    return v / (1.f + __expf(-v));
}

// ---------------------------------------------------------------------------
// One tile of one layer. <=1 tile per block per phase (bid >= NT blocks idle).
// Manual 8-wide K unroll with NAMED loads: guarantees 8 outstanding
// global loads per wave independent of compiler unroll heuristics.
template<int DIN, int DOUT, int KC, int NKY, int PNK, int VEC, bool FINAL,
         int WOFF, int PBOFF, int FBOFF, int NT>
__device__ __forceinline__
void tile_body(const float* __restrict__ hin,   // x or prev partials
               float* __restrict__ outp,        // partials slice, or d_out
               const float* __restrict__ wts,
               const float* __restrict__ bias,
               float* sh)
{
    const int bid = blockIdx.x;
    if (bid >= NT) return;                      // uniform per-block exit
    const int tid = threadIdx.x;

    const int b  = bid & 63;
    const int r  = bid >> 6;
    const int ky = r % NKY;
    const int gx = r / NKY;
    const int k0 = ky * KC;

    // ---- stage h chunk (fused prev-layer reduce + bias + silu) ----
    for (int i = tid; i < KC; i += 128) {
        float s;
        if (PNK == 0) {
            s = hin[b * DIN + k0 + i];
        } else {
            s = bias[b * B_TOTAL_C + PBOFF + k0 + i];
            #pragma unroll
            for (int k = 0; k < PNK; ++k)
                s += hin[((size_t)k * BS + b) * DIN + k0 + i];
            s = silu_f(s);
        }
        sh[i] = s;
    }
    __syncthreads();

    const int o = (gx * 128 + tid) * VEC;
    if (o >= DOUT) return;                      // after the block barrier: ok

    float a0 = 0.f, a1 = 0.f, a2 = 0.f, a3 = 0.f;
    const float* wp = wts + (size_t)b * W_TOTAL_C + WOFF
                          + (size_t)k0 * DOUT + o;

    int i = 0;
    if (VEC == 4) {
        for (; i + 8 <= KC; i += 8) {
            const float4 w0 = *reinterpret_cast<const float4*>(wp + 0 * (size_t)DOUT);
            const float4 w1 = *reinterpret_cast<const float4*>(wp + 1 * (size_t)DOUT);
            const float4 w2 = *reinterpret_cast<const float4*>(wp + 2 * (size_t)DOUT);
            const float4 w3 = *reinterpret_cast<const float4*>(wp + 3 * (size_t)DOUT);
            const float4 w4 = *reinterpret_cast<const float4*>(wp + 4 * (size_t)DOUT);
            const float4 w5 = *reinterpret_cast<const float4*>(wp + 5 * (size_t)DOUT);
            const float4 w6 = *reinterpret_cast<const float4*>(wp + 6 * (size_t)DOUT);
            const float4 w7 = *reinterpret_cast<const float4*>(wp + 7 * (size_t)DOUT);
            const float h0 = sh[i + 0], h1 = sh[i + 1], h2 = sh[i + 2], h3 = sh[i + 3];
            const float h4 = sh[i + 4], h5 = sh[i + 5], h6 = sh[i + 6], h7 = sh[i + 7];
            a0 = fmaf(h0, w0.x, a0); a1 = fmaf(h0, w0.y, a1); a2 = fmaf(h0, w0.z, a2); a3 = fmaf(h0, w0.w, a3);
            a0 = fmaf(h1, w1.x, a0); a1 = fmaf(h1, w1.y, a1); a2 = fmaf(h1, w1.z, a2); a3 = fmaf(h1, w1.w, a3);
            a0 = fmaf(h2, w2.x, a0); a1 = fmaf(h2, w2.y, a1); a2 = fmaf(h2, w2.z, a2); a3 = fmaf(h2, w2.w, a3);
            a0 = fmaf(h3, w3.x, a0); a1 = fmaf(h3, w3.y, a1); a2 = fmaf(h3, w3.z, a2); a3 = fmaf(h3, w3.w, a3);
            a0 = fmaf(h4, w4.x, a0); a1 = fmaf(h4, w4.y, a1); a2 = fmaf(h4, w4.z, a2); a3 = fmaf(h4, w4.w, a3);
            a0 = fmaf(h5, w5.x, a0); a1 = fmaf(h5, w5.y, a1); a2 = fmaf(h5, w5.z, a2); a3 = fmaf(h5, w5.w, a3);
            a0 = fmaf(h6, w6.x, a0); a1 = fmaf(h6, w6.y, a1); a2 = fmaf(h6, w6.z, a2); a3 = fmaf(h6, w6.w, a3);
            a0 = fmaf(h7, w7.x, a0); a1 = fmaf(h7, w7.y, a1); a2 = fmaf(h7, w7.z, a2); a3 = fmaf(h7, w7.w, a3);
            wp += 8 * (size_t)DOUT;
        }
        for (; i < KC; ++i) {
            const float hv = sh[i];
            const float4 w = *reinterpret_cast<const float4*>(wp);
            a0 = fmaf(hv, w.x, a0); a1 = fmaf(hv, w.y, a1);
            a2 = fmaf(hv, w.z, a2); a3 = fmaf(hv, w.w, a3);
            wp += DOUT;
        }
    } else {
        for (; i + 8 <= KC; i += 8) {
            const float2 w0 = *reinterpret_cast<const float2*>(wp + 0 * (size_t)DOUT);
            const float2 w1 = *reinterpret_cast<const float2*>(wp + 1 * (size_t)DOUT);
            const float2 w2 = *reinterpret_cast<const float2*>(wp + 2 * (size_t)DOUT);
            const float2 w3 = *reinterpret_cast<const float2*>(wp + 3 * (size_t)DOUT);
            const float2 w4 = *reinterpret_cast<const float2*>(wp + 4 * (size_t)DOUT);
            const float2 w5 = *reinterpret_cast<const float2*>(wp + 5 * (size_t)DOUT);
            const float2 w6 = *reinterpret_cast<const float2*>(wp + 6 * (size_t)DOUT);
            const float2 w7 = *reinterpret_cast<const float2*>(wp + 7 * (size_t)DOUT);
            const float h0 = sh[i + 0], h1 = sh[i + 1], h2 = sh[i + 2], h3 = sh[i + 3];
            const float h4 = sh[i + 4], h5 = sh[i + 5], h6 = sh[i + 6], h7 = sh[i + 7];
            a0 = fmaf(h0, w0.x, a0); a1 = fmaf(h0, w0.y, a1);
            a0 = fmaf(h1, w1.x, a0); a1 = fmaf(h1, w1.y, a1);
            a0 = fmaf(h2, w2.x, a0); a1 = fmaf(h2, w2.y, a1);
            a0 = fmaf(h3, w3.x, a0); a1 = fmaf(h3, w3.y, a1);
            a0 = fmaf(h4, w4.x, a0); a1 = fmaf(h4, w4.y, a1);
            a0 = fmaf(h5, w5.x, a0); a1 = fmaf(h5, w5.y, a1);
            a0 = fmaf(h6, w6.x, a0); a1 = fmaf(h6, w6.y, a1);
            a0 = fmaf(h7, w7.x, a0); a1 = fmaf(h7, w7.y, a1);
            wp += 8 * (size_t)DOUT;
        }
        for (; i < KC; ++i) {
            const float hv = sh[i];
            const float2 w = *reinterpret_cast<const float2*>(wp);
            a0 = fmaf(hv, w.x, a0); a1 = fmaf(hv, w.y, a1);
            wp += DOUT;
        }
    }

    if (FINAL) {
        float v0 = a0 + bias[b * B_TOTAL_C + FBOFF + o];
        outp[b * DOUT + o] = tanhf(v0);
        if (o + 1 < DOUT) {
            float v1 = a1 + bias[b * B_TOTAL_C + FBOFF + o + 1];
            outp[b * DOUT + o + 1] = tanhf(v1);
        }
    } else {
        float* pp = outp + ((size_t)ky * BS + b) * DOUT + o;
        if (VEC == 4) *reinterpret_cast<float4*>(pp) = make_float4(a0, a1, a2, a3);
        else { pp[0] = a0; pp[1] = a1; }
    }
}

// ---------------------------------------------------------------------------
// Single cooperative kernel: 896 blocks x 128 threads, <=1 tile/block/phase,
// 5 grid-wide barriers, no outer loops.
__global__ __launch_bounds__(128)
void meta_coop(const float* __restrict__ x,
               const float* __restrict__ wts,
               const float* __restrict__ bias,
               float* __restrict__ out,
               float* p0, float* p1, float* p2, float* p3, float* p4)
{
    cg::grid_group grid = cg::this_grid();
    __shared__ float sh[512];

    // P0: L0 1862->512  x->p0   KC=133,NKY=14,VEC=4  (896 tiles, 1:1)
    tile_body<1862,  512, 133, 14,  0, 4, false,       0,    0,    0, 896>(
        x, p0, wts, bias, sh);
    grid.sync();
    // P1: L1 512->256   p0->p1  KC=128,NKY=4,PNK=14  (256 tiles)
    tile_body< 512,  256, 128,  4, 14, 2, false,  953344,    0,    0, 256>(
        p0, p1, wts, bias, sh);
    grid.sync();
    // P2: L2 256->128   p1->p2  KC=64,NKY=4,PNK=4    (256 tiles)
    tile_body< 256,  128,  64,  4,  4, 2, false, 1084416,  512,    0, 256>(
        p1, p2, wts, bias, sh);
    grid.sync();
    // P3: L3 128->256   p2->p3  KC=32,NKY=4,PNK=4    (256 tiles)
    tile_body< 128,  256,  32,  4,  4, 2, false, 1117184,  768,    0, 256>(
        p2, p3, wts, bias, sh);
    grid.sync();
    // P4: L4 256->512   p3->p4  KC=64,NKY=4,PNK=4,GX=2 (512 tiles)
    tile_body< 256,  512,  64,  4,  4, 2, false, 1149952,  896,    0, 512>(
        p3, p4, wts, bias, sh);
    grid.sync();
    // P5: L5 512->1862  p4->out full-K,PNK=4,GX=8,FINAL (512 tiles)
    tile_body< 512, 1862, 512,  1,  4, 2, true,  1281024, 1152, 1664, 512>(
        p4, out, wts, bias, sh);
}

// ---------------------------------------------------------------------------
extern "C" void kernel_launch(void* const* d_in, const int* in_sizes, int n_in,
                              void* d_out, int out_size, void* d_ws, size_t ws_size,
                              hipStream_t stream)
{
    const float* x    = (const float*)d_in[0];   // [64][1862]
    const float* wts  = (const float*)d_in[1];   // [64][W_TOTAL]
    const float* bias = (const float*)d_in[2];   // [64][B_TOTAL]
    float* out = (float*)d_out;                  // [64][1862]

    float* p0 = (float*)d_ws;        // 14*64*512 = 458752
    float* p1 = p0 + 458752;         //  4*64*256 =  65536
    float* p2 = p1 + 65536;          //  4*64*128 =  32768
    float* p3 = p2 + 32768;          //  4*64*256 =  65536
    float* p4 = p3 + 65536;          //  4*64*512 = 131072   (~3.0 MB total)

    void* args[] = { (void*)&x, (void*)&wts, (void*)&bias, (void*)&out,
                     (void*)&p0, (void*)&p1, (void*)&p2, (void*)&p3, (void*)&p4 };
    hipLaunchCooperativeKernel((const void*)meta_coop,
                               dim3(896), dim3(128), args, 0, stream);
}

// Round 16
// 125.124 us; speedup vs baseline: 5.1712x; 5.1712x over previous
//
#include <hip/hip_runtime.h>

#define BS        64
#define W_TOTAL_C 2234368
#define B_TOTAL_C 3526

__device__ __forceinline__ float silu_f(float v) {
    return v / (1.f + __expf(-v));
}

// ---------------------------------------------------------------------------
// One layer, split-K, NO cross-block sync (kernel boundaries order layers).
// K-loop: manual 8-wide unroll with NAMED loads — 8 independent global
// loads issued before their fmas, guaranteeing ILP depth 8 regardless of
// compiler unroll heuristics (R14/R15 showed pragma can silently serialize).
// Accumulation order identical to champion (i ascending) -> bitwise-same.
template<int DIN, int DOUT, int KC, int NK, int PNK, int VEC, int BLK,
         bool FINAL, int WOFF, int PBOFF, int FBOFF>
__global__ __launch_bounds__(BLK)
void layer_kernel(const float* __restrict__ hin,   // x (PNK==0) or prev partials
                  const float* __restrict__ wbase,
                  const float* __restrict__ bias,
                  float* __restrict__ outp)        // this layer's partials, or d_out
{
    __shared__ float sh[KC];

    const int b   = blockIdx.z;
    const int ky  = blockIdx.y;
    const int k0  = ky * KC;
    const int tid = threadIdx.x;

    // ---- stage h chunk (fuse prev layer's reduction + bias + silu) ----
    for (int i = tid; i < KC; i += BLK) {
        float s;
        if (PNK == 0) {
            s = hin[b * DIN + k0 + i];
        } else {
            s = bias[b * B_TOTAL_C + PBOFF + k0 + i];
            #pragma unroll
            for (int k = 0; k < PNK; ++k)
                s += hin[((size_t)k * BS + b) * DIN + k0 + i];
            s = silu_f(s);
        }
        sh[i] = s;
    }
    __syncthreads();

    const int  o      = (blockIdx.x * BLK + tid) * VEC;
    const bool active = (o < DOUT);

    float a0 = 0.f, a1 = 0.f, a2 = 0.f, a3 = 0.f;
    if (active) {
        const float* wp = wbase + (size_t)b * W_TOTAL_C + WOFF
                                + (size_t)k0 * DOUT + o;
        int i = 0;
        if (VEC == 4) {
            for (; i + 8 <= KC; i += 8) {
                const float4 w0 = *reinterpret_cast<const float4*>(wp + 0 * (size_t)DOUT);
                const float4 w1 = *reinterpret_cast<const float4*>(wp + 1 * (size_t)DOUT);
                const float4 w2 = *reinterpret_cast<const float4*>(wp + 2 * (size_t)DOUT);
                const float4 w3 = *reinterpret_cast<const float4*>(wp + 3 * (size_t)DOUT);
                const float4 w4 = *reinterpret_cast<const float4*>(wp + 4 * (size_t)DOUT);
                const float4 w5 = *reinterpret_cast<const float4*>(wp + 5 * (size_t)DOUT);
                const float4 w6 = *reinterpret_cast<const float4*>(wp + 6 * (size_t)DOUT);
                const float4 w7 = *reinterpret_cast<const float4*>(wp + 7 * (size_t)DOUT);
                const float h0 = sh[i + 0], h1 = sh[i + 1], h2 = sh[i + 2], h3 = sh[i + 3];
                const float h4 = sh[i + 4], h5 = sh[i + 5], h6 = sh[i + 6], h7 = sh[i + 7];
                a0 = fmaf(h0, w0.x, a0); a1 = fmaf(h0, w0.y, a1); a2 = fmaf(h0, w0.z, a2); a3 = fmaf(h0, w0.w, a3);
                a0 = fmaf(h1, w1.x, a0); a1 = fmaf(h1, w1.y, a1); a2 = fmaf(h1, w1.z, a2); a3 = fmaf(h1, w1.w, a3);
                a0 = fmaf(h2, w2.x, a0); a1 = fmaf(h2, w2.y, a1); a2 = fmaf(h2, w2.z, a2); a3 = fmaf(h2, w2.w, a3);
                a0 = fmaf(h3, w3.x, a0); a1 = fmaf(h3, w3.y, a1); a2 = fmaf(h3, w3.z, a2); a3 = fmaf(h3, w3.w, a3);
                a0 = fmaf(h4, w4.x, a0); a1 = fmaf(h4, w4.y, a1); a2 = fmaf(h4, w4.z, a2); a3 = fmaf(h4, w4.w, a3);
                a0 = fmaf(h5, w5.x, a0); a1 = fmaf(h5, w5.y, a1); a2 = fmaf(h5, w5.z, a2); a3 = fmaf(h5, w5.w, a3);
                a0 = fmaf(h6, w6.x, a0); a1 = fmaf(h6, w6.y, a1); a2 = fmaf(h6, w6.z, a2); a3 = fmaf(h6, w6.w, a3);
                a0 = fmaf(h7, w7.x, a0); a1 = fmaf(h7, w7.y, a1); a2 = fmaf(h7, w7.z, a2); a3 = fmaf(h7, w7.w, a3);
                wp += 8 * (size_t)DOUT;
            }
            for (; i < KC; ++i) {
                const float hv = sh[i];
                const float4 w = *reinterpret_cast<const float4*>(wp);
                a0 = fmaf(hv, w.x, a0); a1 = fmaf(hv, w.y, a1);
                a2 = fmaf(hv, w.z, a2); a3 = fmaf(hv, w.w, a3);
                wp += DOUT;
            }
        } else {
            for (; i + 8 <= KC; i += 8) {
                const float2 w0 = *reinterpret_cast<const float2*>(wp + 0 * (size_t)DOUT);
                const float2 w1 = *reinterpret_cast<const float2*>(wp + 1 * (size_t)DOUT);
                const float2 w2 = *reinterpret_cast<const float2*>(wp + 2 * (size_t)DOUT);
                const float2 w3 = *reinterpret_cast<const float2*>(wp + 3 * (size_t)DOUT);
                const float2 w4 = *reinterpret_cast<const float2*>(wp + 4 * (size_t)DOUT);
                const float2 w5 = *reinterpret_cast<const float2*>(wp + 5 * (size_t)DOUT);
                const float2 w6 = *reinterpret_cast<const float2*>(wp + 6 * (size_t)DOUT);
                const float2 w7 = *reinterpret_cast<const float2*>(wp + 7 * (size_t)DOUT);
                const float h0 = sh[i + 0], h1 = sh[i + 1], h2 = sh[i + 2], h3 = sh[i + 3];
                const float h4 = sh[i + 4], h5 = sh[i + 5], h6 = sh[i + 6], h7 = sh[i + 7];
                a0 = fmaf(h0, w0.x, a0); a1 = fmaf(h0, w0.y, a1);
                a0 = fmaf(h1, w1.x, a0); a1 = fmaf(h1, w1.y, a1);
                a0 = fmaf(h2, w2.x, a0); a1 = fmaf(h2, w2.y, a1);
                a0 = fmaf(h3, w3.x, a0); a1 = fmaf(h3, w3.y, a1);
                a0 = fmaf(h4, w4.x, a0); a1 = fmaf(h4, w4.y, a1);
                a0 = fmaf(h5, w5.x, a0); a1 = fmaf(h5, w5.y, a1);
                a0 = fmaf(h6, w6.x, a0); a1 = fmaf(h6, w6.y, a1);
                a0 = fmaf(h7, w7.x, a0); a1 = fmaf(h7, w7.y, a1);
                wp += 8 * (size_t)DOUT;
            }
            for (; i < KC; ++i) {
                const float hv = sh[i];
                const float2 w = *reinterpret_cast<const float2*>(wp);
                a0 = fmaf(hv, w.x, a0); a1 = fmaf(hv, w.y, a1);
                wp += DOUT;
            }
        }
    }

    if (!active) return;

    if (FINAL) {
        float v0 = a0 + bias[b * B_TOTAL_C + FBOFF + o];
        outp[b * DOUT + o] = tanhf(v0);
        if (o + 1 < DOUT) {
            float v1 = a1 + bias[b * B_TOTAL_C + FBOFF + o + 1];
            outp[b * DOUT + o + 1] = tanhf(v1);
        }
    } else {
        float* pp = outp + ((size_t)ky * BS + b) * DOUT + o;
        if (VEC == 4) {
            *reinterpret_cast<float4*>(pp) = make_float4(a0, a1, a2, a3);
        } else {
            pp[0] = a0;
            pp[1] = a1;
        }
    }
}

// ---------------------------------------------------------------------------
extern "C" void kernel_launch(void* const* d_in, const int* in_sizes, int n_in,
                              void* d_out, int out_size, void* d_ws, size_t ws_size,
                              hipStream_t stream)
{
    const float* x    = (const float*)d_in[0];   // [64][1862]
    const float* wts  = (const float*)d_in[1];   // [64][W_TOTAL]
    const float* bias = (const float*)d_in[2];   // [64][B_TOTAL]
    float* out = (float*)d_out;                  // [64][1862]

    // partial slices (floats), all plain-store/plain-load, written before read
    float* p0 = (float*)d_ws;        // 7*64*512  = 229376
    float* p1 = p0 + 229376;         // 4*64*256  =  65536
    float* p2 = p1 + 65536;          // 4*64*128  =  32768
    float* p3 = p2 + 32768;          // 4*64*256  =  65536
    float* p4 = p3 + 65536;          // 4*64*512  = 131072  (total 524288 f = 2 MB)

    // L0: 1862 -> 512   (reads x; writes p0)  VEC=4 (16B-aligned rows),
    //     grid 1x7x64 = 448 blocks x 2 waves; exact coverage 128*4 = 512
    layer_kernel<1862, 512, 266, 7, 0, 4, 128, false,       0,    0,    0>
        <<<dim3(1, 7, BS), 128, 0, stream>>>(x, wts, bias, p0);
    // L1: 512 -> 256    (reduce p0 + silu; writes p1)  grid 1x4x64 = 256
    layer_kernel< 512, 256, 128, 4, 7, 2, 128, false,  953344,    0,    0>
        <<<dim3(1, 4, BS), 128, 0, stream>>>(p0, wts, bias, p1);
    // L2: 256 -> 128    (reduce p1; writes p2)          grid 1x4x64 = 256
    layer_kernel< 256, 128,  64, 4, 4, 2,  64, false, 1084416,  512,    0>
        <<<dim3(1, 4, BS),  64, 0, stream>>>(p1, wts, bias, p2);
    // L3: 128 -> 256    (reduce p2; writes p3)          grid 1x4x64 = 256
    layer_kernel< 128, 256,  32, 4, 4, 2, 128, false, 1117184,  768,    0>
        <<<dim3(1, 4, BS), 128, 0, stream>>>(p2, wts, bias, p3);
    // L4: 256 -> 512    (reduce p3; writes p4)          grid 2x4x64 = 512
    layer_kernel< 256, 512,  64, 4, 4, 2, 128, false, 1149952,  896,    0>
        <<<dim3(2, 4, BS), 128, 0, stream>>>(p3, wts, bias, p4);
    // L5: 512 -> 1862   (reduce p4; bias+tanh; writes d_out)  grid 8x1x64 = 512
    layer_kernel< 512, 1862, 512, 1, 4, 2, 128, true, 1281024, 1152, 1664>
        <<<dim3(8, 1, BS), 128, 0, stream>>>(p4, wts, bias, out);
}

// Round 17
// 120.710 us; speedup vs baseline: 5.3603x; 1.0366x over previous
//
#include <hip/hip_runtime.h>

#define BS        64
#define W_TOTAL_C 2234368
#define B_TOTAL_C 3526

__device__ __forceinline__ float silu_f(float v) {
    return v / (1.f + __expf(-v));
}

// ---------------------------------------------------------------------------
// One layer, split-K, NO cross-block sync:
//   - stage h-chunk into LDS; if PNK>0, h is reconstructed as
//     silu( sum_{k<PNK} prev_part[k][b][i] + prev_bias[i] )
//   - K-loop: a[j] += sh[i] * W[b][k0+i][o+j]
//     VEC=2: float2 loads (any even DOUT). VEC=4: float4 loads — ONLY for
//     DOUT%4==0 (16B-aligned rows) with exact coverage.
//   - if FINAL: write tanh(a + bias) straight to d_out
//     else:     write raw partial to this layer's slice (plain stores)
// Visibility across layers comes from kernel boundaries on the stream.
template<int DIN, int DOUT, int KC, int NK, int PNK, int VEC, int BLK,
         bool FINAL, int WOFF, int PBOFF, int FBOFF>
__global__ __launch_bounds__(BLK)
void layer_kernel(const float* __restrict__ hin,   // x (PNK==0) or prev partials
                  const float* __restrict__ wbase,
                  const float* __restrict__ bias,
                  float* __restrict__ outp)        // this layer's partials, or d_out
{
    __shared__ float sh[KC];

    const int b   = blockIdx.z;
    const int ky  = blockIdx.y;
    const int k0  = ky * KC;
    const int tid = threadIdx.x;

    // ---- stage h chunk (fuse prev layer's reduction + bias + silu) ----
    for (int i = tid; i < KC; i += BLK) {
        float s;
        if (PNK == 0) {
            s = hin[b * DIN + k0 + i];
        } else {
            s = bias[b * B_TOTAL_C + PBOFF + k0 + i];
            #pragma unroll
            for (int k = 0; k < PNK; ++k)
                s += hin[((size_t)k * BS + b) * DIN + k0 + i];
            s = silu_f(s);
        }
        sh[i] = s;
    }
    __syncthreads();

    const int  o      = (blockIdx.x * BLK + tid) * VEC;
    const bool active = (o < DOUT);

    float a0 = 0.f, a1 = 0.f, a2 = 0.f, a3 = 0.f;
    if (active) {
        const float* wp = wbase + (size_t)b * W_TOTAL_C + WOFF
                                + (size_t)k0 * DOUT + o;
        if (VEC == 4) {
            #pragma unroll 16
            for (int i = 0; i < KC; ++i) {
                const float hv = sh[i];
                const float4 w = *reinterpret_cast<const float4*>(wp);
                a0 = fmaf(hv, w.x, a0);
                a1 = fmaf(hv, w.y, a1);
                a2 = fmaf(hv, w.z, a2);
                a3 = fmaf(hv, w.w, a3);
                wp += DOUT;
            }
        } else {
            #pragma unroll 16
            for (int i = 0; i < KC; ++i) {
                const float hv = sh[i];
                const float2 w = *reinterpret_cast<const float2*>(wp);
                a0 = fmaf(hv, w.x, a0);
                a1 = fmaf(hv, w.y, a1);
                wp += DOUT;
            }
        }
    }

    if (!active) return;

    if (FINAL) {
        float v0 = a0 + bias[b * B_TOTAL_C + FBOFF + o];
        outp[b * DOUT + o] = tanhf(v0);
        if (o + 1 < DOUT) {
            float v1 = a1 + bias[b * B_TOTAL_C + FBOFF + o + 1];
            outp[b * DOUT + o + 1] = tanhf(v1);
        }
    } else {
        float* pp = outp + ((size_t)ky * BS + b) * DOUT + o;
        if (VEC == 4) {
            *reinterpret_cast<float4*>(pp) = make_float4(a0, a1, a2, a3);
        } else {
            pp[0] = a0;
            pp[1] = a1;
        }
    }
}

// ---------------------------------------------------------------------------
extern "C" void kernel_launch(void* const* d_in, const int* in_sizes, int n_in,
                              void* d_out, int out_size, void* d_ws, size_t ws_size,
                              hipStream_t stream)
{
    const float* x    = (const float*)d_in[0];   // [64][1862]
    const float* wts  = (const float*)d_in[1];   // [64][W_TOTAL]
    const float* bias = (const float*)d_in[2];   // [64][B_TOTAL]
    float* out = (float*)d_out;                  // [64][1862]

    // partial slices (floats), all plain-store/plain-load, written before read
    float* p0 = (float*)d_ws;        // 7*64*512  = 229376
    float* p1 = p0 + 229376;         // 4*64*256  =  65536
    float* p2 = p1 + 65536;          // 4*64*128  =  32768
    float* p3 = p2 + 32768;          // 4*64*256  =  65536
    float* p4 = p3 + 65536;          // 4*64*512  = 131072  (total 524288 f = 2 MB)

    // L0: 1862 -> 512   (reads x; writes p0)  VEC=4 (16B-aligned rows),
    //     grid 1x7x64 = 448 blocks x 2 waves; exact coverage 128*4 = 512
    layer_kernel<1862, 512, 266, 7, 0, 4, 128, false,       0,    0,    0>
        <<<dim3(1, 7, BS), 128, 0, stream>>>(x, wts, bias, p0);
    // L1: 512 -> 256    (reduce p0 + silu; writes p1)  grid 1x4x64 = 256
    layer_kernel< 512, 256, 128, 4, 7, 2, 128, false,  953344,    0,    0>
        <<<dim3(1, 4, BS), 128, 0, stream>>>(p0, wts, bias, p1);
    // L2: 256 -> 128    (reduce p1; writes p2)          grid 1x4x64 = 256
    layer_kernel< 256, 128,  64, 4, 4, 2,  64, false, 1084416,  512,    0>
        <<<dim3(1, 4, BS),  64, 0, stream>>>(p1, wts, bias, p2);
    // L3: 128 -> 256    (reduce p2; writes p3)          grid 1x4x64 = 256
    layer_kernel< 128, 256,  32, 4, 4, 2, 128, false, 1117184,  768,    0>
        <<<dim3(1, 4, BS), 128, 0, stream>>>(p2, wts, bias, p3);
    // L4: 256 -> 512    (reduce p3; writes p4)          grid 2x4x64 = 512
    layer_kernel< 256, 512,  64, 4, 4, 2, 128, false, 1149952,  896,    0>
        <<<dim3(2, 4, BS), 128, 0, stream>>>(p3, wts, bias, p4);
    // L5: 512 -> 1862   (reduce p4; bias+tanh; writes d_out)  grid 8x1x64 = 512
    layer_kernel< 512, 1862, 512, 1, 4, 2, 128, true, 1281024, 1152, 1664>
        <<<dim3(8, 1, BS), 128, 0, stream>>>(p4, wts, bias, out);
}